// Round 21
// baseline (59.266 us; speedup 1.0000x reference)
//
#include <hip/hip_runtime.h>
#include <math.h>

#define A_N 2048
#define NLAYERS 2057

// ws layout (4B units; float and int offsets coincide)
#define PART_OFF  0               // 2049*256 (row 0 = middle+chain, 1+idx = expert idx)
#define PART2_OFF 524544          // 64*256
#define GSUM_OFF  540928
#define WSUM_OFF  540929
#define NACTI_OFF 540930          // int: number of active experts
#define LISTI_OFF 540932          // int[2048]: compacted active expert ids

typedef float f4 __attribute__((ext_vector_type(4)));

// pull nf4 float4s at base into cache (stride = nthr)
__device__ __forceinline__ void warmN(const float* base, int nf4, int t, int nthr)
{
    const f4* p = (const f4*)base;
    for (int i = t; i < nf4; i += nthr) {
        f4 v = p[i];
        asm volatile("" :: "v"(v.x), "v"(v.y), "v"(v.z), "v"(v.w));
    }
}

// ---- shared building blocks (256-thread blocks, 4 waves) ----

// softmax-2 head: dest[0..1] = softmax(sx @ W2 + b2) * scale
__device__ __forceinline__ void head256(const float* sx, float* r0, float* r1,
                                        const float* W2, const float* b2,
                                        float scale, float* dest, int t)
{
    float xv = sx[t];
    r0[t] = xv * W2[2*t];
    r1[t] = xv * W2[2*t+1];
    __syncthreads();
    for (int s = 128; s > 0; s >>= 1) {
        if (t < s) { r0[t] += r0[t+s]; r1[t] += r1[t+s]; }
        __syncthreads();
    }
    if (t == 0) {
        float o0 = r0[0] + b2[0], o1 = r1[0] + b2[1];
        float m  = fmaxf(o0, o1);
        float e0 = expf(o0 - m), e1 = expf(o1 - m);
        float inv = scale / (e0 + e1);
        dest[0] = e0 * inv;
        dest[1] = e1 * inv;
    }
    __syncthreads();
}

// compact nonzero rows: rlist/gl get the != 0 entries, padded tail of 32 zeros
__device__ __forceinline__ int compact_nz(float val, int t, int quad, int lane,
                                          int* rlist, float* gl, int* swcnt)
{
    bool pred = (val != 0.f);
    unsigned long long m = __ballot(pred);
    if (lane == 0) swcnt[quad] = (int)__popcll(m);
    __syncthreads();
    int nr = swcnt[0] + swcnt[1] + swcnt[2] + swcnt[3];
    int offs = 0;
    #pragma unroll
    for (int q2 = 0; q2 < 4; ++q2) if (q2 < quad) offs += swcnt[q2];
    int rank = (int)__popcll(m & ((1ull << lane) - 1ull));
    if (pred) { rlist[offs + rank] = t; gl[offs + rank] = val; }
    if (t < 32) { rlist[nr + t] = 0; gl[nr + t] = 0.f; }   // padded tail (g=0)
    __syncthreads();
    return nr;
}

// gated row-gather mat-vec partial: 8 batched 1KB row reads per iteration
__device__ __forceinline__ f4 gather8(const f4* Wb, const int* rlist,
                                      const float* gl, int nr, int quad)
{
    f4 acc = {0.f, 0.f, 0.f, 0.f};
    int niter = (nr + 31) >> 5;         // 32 rows/iter (8 per wave)
    for (int it = 0; it < niter; ++it) {
        int base = it*32 + quad*8;
        int r0 = rlist[base+0], r1 = rlist[base+1], r2 = rlist[base+2], r3 = rlist[base+3];
        int r4 = rlist[base+4], r5 = rlist[base+5], r6 = rlist[base+6], r7 = rlist[base+7];
        float g0 = gl[base+0], g1 = gl[base+1], g2 = gl[base+2], g3 = gl[base+3];
        float g4 = gl[base+4], g5 = gl[base+5], g6 = gl[base+6], g7 = gl[base+7];
        f4 v0 = Wb[(size_t)r0*64]; f4 v1 = Wb[(size_t)r1*64];
        f4 v2 = Wb[(size_t)r2*64]; f4 v3 = Wb[(size_t)r3*64];
        f4 v4 = Wb[(size_t)r4*64]; f4 v5 = Wb[(size_t)r5*64];
        f4 v6 = Wb[(size_t)r6*64]; f4 v7 = Wb[(size_t)r7*64];
        acc += g0*v0 + g1*v1 + g2*v2 + g3*v3 + g4*v4 + g5*v5 + g6*v6 + g7*v7;
    }
    return acc;
}

// NT variant for the once-read Wef slabs: bypass cache allocation
__device__ __forceinline__ f4 gather8nt(const f4* Wb, const int* rlist,
                                        const float* gl, int nr, int quad)
{
    f4 acc = {0.f, 0.f, 0.f, 0.f};
    int niter = (nr + 31) >> 5;         // 32 rows/iter (8 per wave)
    for (int it = 0; it < niter; ++it) {
        int base = it*32 + quad*8;
        int r0 = rlist[base+0], r1 = rlist[base+1], r2 = rlist[base+2], r3 = rlist[base+3];
        int r4 = rlist[base+4], r5 = rlist[base+5], r6 = rlist[base+6], r7 = rlist[base+7];
        float g0 = gl[base+0], g1 = gl[base+1], g2 = gl[base+2], g3 = gl[base+3];
        float g4 = gl[base+4], g5 = gl[base+5], g6 = gl[base+6], g7 = gl[base+7];
        f4 v0 = __builtin_nontemporal_load(&Wb[(size_t)r0*64]);
        f4 v1 = __builtin_nontemporal_load(&Wb[(size_t)r1*64]);
        f4 v2 = __builtin_nontemporal_load(&Wb[(size_t)r2*64]);
        f4 v3 = __builtin_nontemporal_load(&Wb[(size_t)r3*64]);
        f4 v4 = __builtin_nontemporal_load(&Wb[(size_t)r4*64]);
        f4 v5 = __builtin_nontemporal_load(&Wb[(size_t)r5*64]);
        f4 v6 = __builtin_nontemporal_load(&Wb[(size_t)r6*64]);
        f4 v7 = __builtin_nontemporal_load(&Wb[(size_t)r7*64]);
        acc += g0*v0 + g1*v1 + g2*v2 + g3*v3 + g4*v4 + g5*v5 + g6*v6 + g7*v7;
    }
    return acc;
}

// ---- kernel 0: block 0 = compaction + sums + zeroing; blocks 1..21 warm chain;
//      blocks 22..35 warm end-stack weights ----
__global__ __launch_bounds__(1024) void k_list(const int* __restrict__ Xm,
                                               const float* __restrict__ lw,
                                               const float* __restrict__ Wbr,
                                               const float* __restrict__ Wm,
                                               const float* __restrict__ Wbo,
                                               const float* __restrict__ Wmo,
                                               const float* __restrict__ Wef,
                                               const float* __restrict__ Wer,
                                               const float* __restrict__ Weo,
                                               const float* __restrict__ bef,
                                               const float* __restrict__ ber,
                                               const float* __restrict__ beo,
                                               float* __restrict__ out,
                                               float* __restrict__ ws)
{
    int t = threadIdx.x, b = blockIdx.x;
    if (b > 0) {
        if (b <= 21) {
            int wi = b - 1;             // 64KB (4096 f4) slices
            if      (wi < 12) warmN(Wbr + (size_t)wi * 16384, 4096, t, 1024);        // 768KB
            else if (wi < 16) warmN(Wm + (size_t)(wi - 12) * 16384, 4096, t, 1024);  // 256KB
            else if (wi == 16) { warmN(Wbo, 512, t, 1024); warmN(Wmo, 128, t, 1024); }
            else warmN(Wef + (size_t)A_N * 65536 + (size_t)(wi - 17) * 16384, 4096, t, 1024);
        } else {
            int wi = b - 22;            // end-stack weights, 768KB + small
            if      (wi < 12) warmN(Wer + (size_t)wi * 16384, 4096, t, 1024);
            else if (wi == 12) { warmN(Weo, 512, t, 1024); warmN(bef, 64, t, 1024); }
            else { warmN(ber, 192, t, 1024); warmN(beo, 2, t, 1024); }
        }
        return;
    }
    __shared__ int scan[1024];
    __shared__ float fred[1024];
    int e0 = 2*t, e1 = 2*t + 1;
    int a0 = (Xm[e0] != 0) ? 1 : 0;
    int a1 = (Xm[e1] != 0) ? 1 : 0;
    int s = a0 + a1;
    scan[t] = s;
    fred[t] = (a0 ? lw[4+e0] : 0.f) + (a1 ? lw[4+e1] : 0.f);
    __syncthreads();
    for (int off = 1; off < 1024; off <<= 1) {
        int v = (t >= off) ? scan[t-off] : 0;
        __syncthreads();
        scan[t] += v;
        __syncthreads();
    }
    for (int ss = 512; ss > 0; ss >>= 1) {
        if (t < ss) fred[t] += fred[t+ss];
        __syncthreads();
    }
    int total = scan[1023];
    int excl  = scan[t] - s;
    int* list = (int*)ws + LISTI_OFF;
    if (a0) list[excl] = e0;
    else    { out[2 + (4+e0)*2] = 0.f; out[2 + (4+e0)*2 + 1] = 0.f; }
    if (a1) list[excl + a0] = e1;
    else    { out[2 + (4+e1)*2] = 0.f; out[2 + (4+e1)*2 + 1] = 0.f; }
    if (t == 0) {
        ((int*)ws)[NACTI_OFF] = total;
        float gaux = fred[0];
        ws[GSUM_OFF] = gaux + lw[2056];
        ws[WSUM_OFF] = lw[0]+lw[1]+lw[2]+lw[3] + gaux
                     + lw[2052]+lw[2053]+lw[2054]+lw[2055]+lw[2056];
    }
}

// ---- kernel 1: block 0 = gated chain + middle chunk; 1..2048 = experts ----
// 4 blocks/CU (no LDS pad) + NT Wef reads: A/B on stream count in the NT regime.
__global__ __launch_bounds__(256, 4) void k_mainc(
    const float* __restrict__ X,
    const float* __restrict__ bfv,
    const float* __restrict__ Wbf, const float* __restrict__ bbf,
    const float* __restrict__ Wbr, const float* __restrict__ bbr,
    const float* __restrict__ Wbo, const float* __restrict__ bbo,
    const float* __restrict__ Wm, const float* __restrict__ bm,
    const float* __restrict__ Wmo, const float* __restrict__ bmo,
    const float* __restrict__ Wa, const float* __restrict__ ba,
    const float* __restrict__ Wao, const float* __restrict__ bao,
    const float* __restrict__ Wef, const float* __restrict__ lw,
    float* __restrict__ out, float* __restrict__ ws)
{
    __shared__ float sg[256];
    __shared__ float sacc[4][256];
    __shared__ float gl[288];
    __shared__ int   rlist[288];
    __shared__ int   swcnt[4];
    int b = blockIdx.x, t = threadIdx.x;
    int quad = t >> 6, lane = t & 63;
    float* part = ws + PART_OFF;

    if (b == 0) {
        // ---- base stack + middle, ReLU-gated gather matvecs (L3-warm) ----
        sg[t] = fmaxf(bfv[0] * Wbf[t] + bbf[t], 0.f);
        __syncthreads();
        head256(sg, sacc[0], sacc[1], Wbo, bbo, lw[0], out + 2, t);

        #define MV_GATED(W, B)                                                  \
        {                                                                       \
            int nr = compact_nz(sg[t], t, quad, lane, rlist, gl, swcnt);        \
            f4 a = gather8((const f4*)(W) + lane, rlist, gl, nr, quad);         \
            sacc[quad][lane*4+0] = a.x; sacc[quad][lane*4+1] = a.y;             \
            sacc[quad][lane*4+2] = a.z; sacc[quad][lane*4+3] = a.w;             \
            __syncthreads();                                                    \
            float v = fmaxf(sacc[0][t] + sacc[1][t] + sacc[2][t] + sacc[3][t]   \
                            + (B)[t], 0.f);                                     \
            __syncthreads();                                                    \
            sg[t] = v;                                                          \
            __syncthreads();                                                    \
        }

        for (int i = 0; i < 3; ++i) {
            MV_GATED(Wbr + i*65536, bbr + i*256);
            head256(sg, sacc[0], sacc[1], Wbo + (i+1)*512, bbo + (i+1)*2,
                    lw[i+1], out + 2 + (i+1)*2, t);
        }
        MV_GATED(Wm, bm);
        head256(sg, sacc[0], sacc[1], Wmo, bmo, lw[2056], out + 2 + 2056*2, t);

        // middle We_first chunk -> part row 0, gated by sg*lw[2056]
        {
            int nr = compact_nz(sg[t] * lw[2056], t, quad, lane, rlist, gl, swcnt);
            f4 a = gather8((const f4*)(Wef + (size_t)A_N * 65536) + lane,
                           rlist, gl, nr, quad);
            sacc[quad][lane*4+0] = a.x; sacc[quad][lane*4+1] = a.y;
            sacc[quad][lane*4+2] = a.z; sacc[quad][lane*4+3] = a.w;
            __syncthreads();
            part[t] = sacc[0][t] + sacc[1][t] + sacc[2][t] + sacc[3][t];
        }
        return;
    }

    // ---- expert path (compacted): idx = b-1 ----
    int idx = b - 1;
    int nact = ((const int*)ws)[NACTI_OFF];
    if (idx >= nact) return;            // instant exit (k_list zeroed out rows)
    int e = ((const int*)ws + LISTI_OFF)[idx];

    float xv = X[e];
    float w  = lw[4 + e];
    float h  = fmaxf(xv * Wa[e*256 + t] + ba[e*256 + t], 0.f);
    float2 wo = *(const float2*)&Wao[(size_t)e*512 + 2*t];
    sacc[0][t] = h * wo.x;
    sacc[1][t] = h * wo.y;
    __syncthreads();
    for (int s = 128; s > 0; s >>= 1) {
        if (t < s) { sacc[0][t] += sacc[0][t+s]; sacc[1][t] += sacc[1][t+s]; }
        __syncthreads();
    }
    if (t == 0) {
        float o0 = sacc[0][0] + bao[2*e], o1 = sacc[1][0] + bao[2*e+1];
        float m  = fmaxf(o0, o1);
        float e0 = expf(o0 - m), e1 = expf(o1 - m);
        float inv = w / (e0 + e1);      // * lw * mask; /wsum deferred
        out[2 + (4+e)*2]     = e0 * inv;
        out[2 + (4+e)*2 + 1] = e1 * inv;
    }
    float val = h * w;
    __syncthreads();

    int nr = compact_nz(val, t, quad, lane, rlist, gl, swcnt);
    f4 acc = gather8nt((const f4*)(Wef + (size_t)e * 65536) + lane, rlist, gl, nr, quad);
    sacc[quad][lane*4+0] = acc.x; sacc[quad][lane*4+1] = acc.y;
    sacc[quad][lane*4+2] = acc.z; sacc[quad][lane*4+3] = acc.w;
    __syncthreads();
    float pv = sacc[0][t] + sacc[1][t] + sacc[2][t] + sacc[3][t];
    __builtin_nontemporal_store(pv, &part[(size_t)(1+idx)*256 + t]);
}

// ---- kernel 2: pure reduce part rows 0..nact -> part2[64][256] ----
__global__ __launch_bounds__(256) void k_red(float* __restrict__ ws)
{
    int r = blockIdx.x, t = threadIdx.x;
    int nact = ((const int*)ws)[NACTI_OFF];
    float acc = 0.f;
    for (int j = r; j <= nact; j += 64) {
        acc += ws[PART_OFF + (size_t)j*256 + t];
    }
    ws[PART2_OFF + r*256 + t] = acc;
}

// ---- kernel 3: end stack + final combine (1 block x 1024, f4 matvecs) ----
__global__ __launch_bounds__(1024) void k_end(
    const float* __restrict__ bef, const float* __restrict__ Wer,
    const float* __restrict__ ber, const float* __restrict__ Weo,
    const float* __restrict__ beo, const float* __restrict__ lw,
    float* __restrict__ out, float* __restrict__ ws)
{
    __shared__ float sx[256];
    __shared__ float wacc[16][256];
    __shared__ float red0[1024], red1[1024];
    __shared__ float endraw[4][2];
    int tid = threadIdx.x;
    int w = tid >> 6, l = tid & 63;     // 16 waves x 64 lanes
    int q = tid >> 8, t = tid & 255;

    // ---- finish reduce: part2[64][256] -> sx, /gsum, bias, relu ----
    float acc = 0.f;
    #pragma unroll
    for (int j = 0; j < 16; ++j) acc += ws[PART2_OFF + (q*16 + j)*256 + t];
    wacc[q][t] = acc;
    __syncthreads();
    float gsum = ws[GSUM_OFF];
    if (tid < 256) {
        float v = wacc[0][t] + wacc[1][t] + wacc[2][t] + wacc[3][t];
        sx[t] = fmaxf(v / gsum + bef[t], 0.f);
    }
    __syncthreads();

    #define HEAD_G(W2, B2, SCALE, DEST)                                         \
    {                                                                           \
        if (tid < 256) { red0[tid] = sx[tid]*(W2)[2*tid]; red1[tid] = sx[tid]*(W2)[2*tid+1]; } \
        __syncthreads();                                                        \
        for (int s = 128; s > 0; s >>= 1) {                                     \
            if (tid < s) { red0[tid] += red0[tid+s]; red1[tid] += red1[tid+s]; }\
            __syncthreads();                                                    \
        }                                                                       \
        if (tid == 0) {                                                         \
            float o0 = red0[0] + (B2)[0], o1 = red1[0] + (B2)[1];               \
            float m  = fmaxf(o0, o1);                                           \
            float e0 = expf(o0 - m), e1 = expf(o1 - m);                         \
            float inv = (SCALE) / (e0 + e1);                                    \
            (DEST)[0] = e0 * inv; (DEST)[1] = e1 * inv;                         \
        }                                                                       \
        __syncthreads();                                                        \
    }

    // 16-way wave-K-split f4 matvec (fat registers OK in this standalone kernel)
    #define MV_E(W, B)                                                          \
    {                                                                           \
        const f4* Wv = (const f4*)(W);                                          \
        f4 a4 = {0.f, 0.f, 0.f, 0.f};                                           \
        _Pragma("unroll 16")                                                    \
        for (int kk = 0; kk < 16; ++kk) {                                       \
            int k = w*16 + kk;                                                  \
            float xv = sx[k];                                                   \
            f4 wv = Wv[k*64 + l];                                               \
            a4 += xv * wv;                                                      \
        }                                                                       \
        wacc[w][4*l+0] = a4.x; wacc[w][4*l+1] = a4.y;                           \
        wacc[w][4*l+2] = a4.z; wacc[w][4*l+3] = a4.w;                           \
        __syncthreads();                                                        \
        if (tid < 256) {                                                        \
            float v = 0.f;                                                      \
            _Pragma("unroll 16")                                                \
            for (int j = 0; j < 16; ++j) v += wacc[j][tid];                     \
            sx[tid] = fmaxf(v + (B)[tid], 0.f);                                 \
        }                                                                       \
        __syncthreads();                                                        \
    }

    HEAD_G(Weo, beo, lw[2052], &endraw[0][0]);
    for (int i = 0; i < 3; ++i) {
        MV_E(Wer + i*65536, ber + i*256);
        HEAD_G(Weo + (i+1)*512, beo + (i+1)*2, lw[2053 + i], &endraw[i+1][0]);
    }

    // ---- rescale all rows by 1/wsum, accumulate final logit ----
    float invw = 1.f / ws[WSUM_OFF];
    float s0 = 0.f, s1 = 0.f;
    for (int i = tid; i < NLAYERS; i += 1024) {
        float v0, v1;
        if (i >= 2052 && i < 2056) { v0 = endraw[i-2052][0]; v1 = endraw[i-2052][1]; }
        else                        { v0 = out[2 + 2*i];      v1 = out[2 + 2*i + 1]; }
        v0 *= invw; v1 *= invw;
        out[2 + 2*i]     = v0;
        out[2 + 2*i + 1] = v1;
        s0 += v0; s1 += v1;
    }
    red0[tid] = s0; red1[tid] = s1; __syncthreads();
    for (int s = 512; s > 0; s >>= 1) {
        if (tid < s) { red0[tid] += red0[tid+s]; red1[tid] += red1[tid+s]; }
        __syncthreads();
    }
    if (tid == 0) { out[0] = red0[0]; out[1] = red1[0]; }
}

extern "C" void kernel_launch(void* const* d_in, const int* in_sizes, int n_in,
                              void* d_out, int out_size, void* d_ws, size_t ws_size,
                              hipStream_t stream)
{
    const float* X    = (const float*)d_in[0];
    const int*   Xm   = (const int*)  d_in[1];
    const float* bfv  = (const float*)d_in[2];
    const float* Wbf  = (const float*)d_in[3];
    const float* bbf  = (const float*)d_in[4];
    const float* Wbr  = (const float*)d_in[5];
    const float* bbr  = (const float*)d_in[6];
    const float* Wbo  = (const float*)d_in[7];
    const float* bbo  = (const float*)d_in[8];
    const float* Wm   = (const float*)d_in[9];
    const float* bm   = (const float*)d_in[10];
    const float* Wmo  = (const float*)d_in[11];
    const float* bmo  = (const float*)d_in[12];
    const float* Wa   = (const float*)d_in[13];
    const float* ba   = (const float*)d_in[14];
    const float* Wao  = (const float*)d_in[15];
    const float* bao  = (const float*)d_in[16];
    const float* Wef  = (const float*)d_in[17];
    const float* bef  = (const float*)d_in[18];
    const float* Wer  = (const float*)d_in[19];
    const float* ber  = (const float*)d_in[20];
    const float* Weo  = (const float*)d_in[21];
    const float* beo  = (const float*)d_in[22];
    const float* lw   = (const float*)d_in[23];
    float* out = (float*)d_out;
    float* wsf = (float*)d_ws;

    k_list<<<36, 1024, 0, stream>>>(Xm, lw, Wbr, Wm, Wbo, Wmo, Wef,
                                    Wer, Weo, bef, ber, beo, out, wsf);
    k_mainc<<<A_N + 1, 256, 0, stream>>>(X, bfv, Wbf, bbf, Wbr, bbr, Wbo, bbo,
                                         Wm, bm, Wmo, bmo, Wa, ba, Wao, bao,
                                         Wef, lw, out, wsf);
    k_red<<<64, 256, 0, stream>>>(wsf);
    k_end<<<1, 1024, 0, stream>>>(bef, Wer, ber, Weo, beo, lw, out, wsf);
}

// Round 22
// 55.980 us; speedup vs baseline: 1.0587x; 1.0587x over previous
//
#include <hip/hip_runtime.h>
#include <math.h>

#define A_N 2048
#define NLAYERS 2057

// ws layout (4B units; float and int offsets coincide)
#define PART_OFF  0               // 2049*256 (row 0 = middle+chain, 1+idx = expert idx)
#define PART2_OFF 524544          // 64*256
#define GSUM_OFF  540928
#define WSUM_OFF  540929
#define NACTI_OFF 540930          // int: number of active experts
#define LISTI_OFF 540932          // int[2048]: compacted active expert ids

typedef float f4 __attribute__((ext_vector_type(4)));

// pull nf4 float4s at base into cache (stride = nthr)
__device__ __forceinline__ void warmN(const float* base, int nf4, int t, int nthr)
{
    const f4* p = (const f4*)base;
    for (int i = t; i < nf4; i += nthr) {
        f4 v = p[i];
        asm volatile("" :: "v"(v.x), "v"(v.y), "v"(v.z), "v"(v.w));
    }
}

// ---- shared building blocks (256-thread blocks, 4 waves) ----

// softmax-2 head: dest[0..1] = softmax(sx @ W2 + b2) * scale
__device__ __forceinline__ void head256(const float* sx, float* r0, float* r1,
                                        const float* W2, const float* b2,
                                        float scale, float* dest, int t)
{
    float xv = sx[t];
    r0[t] = xv * W2[2*t];
    r1[t] = xv * W2[2*t+1];
    __syncthreads();
    for (int s = 128; s > 0; s >>= 1) {
        if (t < s) { r0[t] += r0[t+s]; r1[t] += r1[t+s]; }
        __syncthreads();
    }
    if (t == 0) {
        float o0 = r0[0] + b2[0], o1 = r1[0] + b2[1];
        float m  = fmaxf(o0, o1);
        float e0 = expf(o0 - m), e1 = expf(o1 - m);
        float inv = scale / (e0 + e1);
        dest[0] = e0 * inv;
        dest[1] = e1 * inv;
    }
    __syncthreads();
}

// compact nonzero rows: rlist/gl get the != 0 entries, padded tail of 32 zeros
__device__ __forceinline__ int compact_nz(float val, int t, int quad, int lane,
                                          int* rlist, float* gl, int* swcnt)
{
    bool pred = (val != 0.f);
    unsigned long long m = __ballot(pred);
    if (lane == 0) swcnt[quad] = (int)__popcll(m);
    __syncthreads();
    int nr = swcnt[0] + swcnt[1] + swcnt[2] + swcnt[3];
    int offs = 0;
    #pragma unroll
    for (int q2 = 0; q2 < 4; ++q2) if (q2 < quad) offs += swcnt[q2];
    int rank = (int)__popcll(m & ((1ull << lane) - 1ull));
    if (pred) { rlist[offs + rank] = t; gl[offs + rank] = val; }
    if (t < 32) { rlist[nr + t] = 0; gl[nr + t] = 0.f; }   // padded tail (g=0)
    __syncthreads();
    return nr;
}

// gated row-gather mat-vec partial: 8 batched 1KB row reads per iteration
__device__ __forceinline__ f4 gather8(const f4* Wb, const int* rlist,
                                      const float* gl, int nr, int quad)
{
    f4 acc = {0.f, 0.f, 0.f, 0.f};
    int niter = (nr + 31) >> 5;         // 32 rows/iter (8 per wave)
    for (int it = 0; it < niter; ++it) {
        int base = it*32 + quad*8;
        int r0 = rlist[base+0], r1 = rlist[base+1], r2 = rlist[base+2], r3 = rlist[base+3];
        int r4 = rlist[base+4], r5 = rlist[base+5], r6 = rlist[base+6], r7 = rlist[base+7];
        float g0 = gl[base+0], g1 = gl[base+1], g2 = gl[base+2], g3 = gl[base+3];
        float g4 = gl[base+4], g5 = gl[base+5], g6 = gl[base+6], g7 = gl[base+7];
        f4 v0 = Wb[(size_t)r0*64]; f4 v1 = Wb[(size_t)r1*64];
        f4 v2 = Wb[(size_t)r2*64]; f4 v3 = Wb[(size_t)r3*64];
        f4 v4 = Wb[(size_t)r4*64]; f4 v5 = Wb[(size_t)r5*64];
        f4 v6 = Wb[(size_t)r6*64]; f4 v7 = Wb[(size_t)r7*64];
        acc += g0*v0 + g1*v1 + g2*v2 + g3*v3 + g4*v4 + g5*v5 + g6*v6 + g7*v7;
    }
    return acc;
}

// NT variant for the once-read Wef slabs: bypass cache allocation
__device__ __forceinline__ f4 gather8nt(const f4* Wb, const int* rlist,
                                        const float* gl, int nr, int quad)
{
    f4 acc = {0.f, 0.f, 0.f, 0.f};
    int niter = (nr + 31) >> 5;         // 32 rows/iter (8 per wave)
    for (int it = 0; it < niter; ++it) {
        int base = it*32 + quad*8;
        int r0 = rlist[base+0], r1 = rlist[base+1], r2 = rlist[base+2], r3 = rlist[base+3];
        int r4 = rlist[base+4], r5 = rlist[base+5], r6 = rlist[base+6], r7 = rlist[base+7];
        float g0 = gl[base+0], g1 = gl[base+1], g2 = gl[base+2], g3 = gl[base+3];
        float g4 = gl[base+4], g5 = gl[base+5], g6 = gl[base+6], g7 = gl[base+7];
        f4 v0 = __builtin_nontemporal_load(&Wb[(size_t)r0*64]);
        f4 v1 = __builtin_nontemporal_load(&Wb[(size_t)r1*64]);
        f4 v2 = __builtin_nontemporal_load(&Wb[(size_t)r2*64]);
        f4 v3 = __builtin_nontemporal_load(&Wb[(size_t)r3*64]);
        f4 v4 = __builtin_nontemporal_load(&Wb[(size_t)r4*64]);
        f4 v5 = __builtin_nontemporal_load(&Wb[(size_t)r5*64]);
        f4 v6 = __builtin_nontemporal_load(&Wb[(size_t)r6*64]);
        f4 v7 = __builtin_nontemporal_load(&Wb[(size_t)r7*64]);
        acc += g0*v0 + g1*v1 + g2*v2 + g3*v3 + g4*v4 + g5*v5 + g6*v6 + g7*v7;
    }
    return acc;
}

// ---- kernel 0: block 0 = compaction + sums + zeroing; blocks 1..21 warm chain;
//      blocks 22..35 warm end-stack weights (NT stream no longer evicts them) ----
__global__ __launch_bounds__(1024) void k_list(const int* __restrict__ Xm,
                                               const float* __restrict__ lw,
                                               const float* __restrict__ Wbr,
                                               const float* __restrict__ Wm,
                                               const float* __restrict__ Wbo,
                                               const float* __restrict__ Wmo,
                                               const float* __restrict__ Wef,
                                               const float* __restrict__ Wer,
                                               const float* __restrict__ Weo,
                                               const float* __restrict__ bef,
                                               const float* __restrict__ ber,
                                               const float* __restrict__ beo,
                                               float* __restrict__ out,
                                               float* __restrict__ ws)
{
    int t = threadIdx.x, b = blockIdx.x;
    if (b > 0) {
        if (b <= 21) {
            int wi = b - 1;             // 64KB (4096 f4) slices
            if      (wi < 12) warmN(Wbr + (size_t)wi * 16384, 4096, t, 1024);        // 768KB
            else if (wi < 16) warmN(Wm + (size_t)(wi - 12) * 16384, 4096, t, 1024);  // 256KB
            else if (wi == 16) { warmN(Wbo, 512, t, 1024); warmN(Wmo, 128, t, 1024); }
            else warmN(Wef + (size_t)A_N * 65536 + (size_t)(wi - 17) * 16384, 4096, t, 1024);
        } else {
            int wi = b - 22;            // end-stack weights, 768KB + small
            if      (wi < 12) warmN(Wer + (size_t)wi * 16384, 4096, t, 1024);
            else if (wi == 12) { warmN(Weo, 512, t, 1024); warmN(bef, 64, t, 1024); }
            else { warmN(ber, 192, t, 1024); warmN(beo, 2, t, 1024); }
        }
        return;
    }
    __shared__ int scan[1024];
    __shared__ float fred[1024];
    int e0 = 2*t, e1 = 2*t + 1;
    int a0 = (Xm[e0] != 0) ? 1 : 0;
    int a1 = (Xm[e1] != 0) ? 1 : 0;
    int s = a0 + a1;
    scan[t] = s;
    fred[t] = (a0 ? lw[4+e0] : 0.f) + (a1 ? lw[4+e1] : 0.f);
    __syncthreads();
    for (int off = 1; off < 1024; off <<= 1) {
        int v = (t >= off) ? scan[t-off] : 0;
        __syncthreads();
        scan[t] += v;
        __syncthreads();
    }
    for (int ss = 512; ss > 0; ss >>= 1) {
        if (t < ss) fred[t] += fred[t+ss];
        __syncthreads();
    }
    int total = scan[1023];
    int excl  = scan[t] - s;
    int* list = (int*)ws + LISTI_OFF;
    if (a0) list[excl] = e0;
    else    { out[2 + (4+e0)*2] = 0.f; out[2 + (4+e0)*2 + 1] = 0.f; }
    if (a1) list[excl + a0] = e1;
    else    { out[2 + (4+e1)*2] = 0.f; out[2 + (4+e1)*2 + 1] = 0.f; }
    if (t == 0) {
        ((int*)ws)[NACTI_OFF] = total;
        float gaux = fred[0];
        ws[GSUM_OFF] = gaux + lw[2056];
        ws[WSUM_OFF] = lw[0]+lw[1]+lw[2]+lw[3] + gaux
                     + lw[2052]+lw[2053]+lw[2054]+lw[2055]+lw[2056];
    }
}

// ---- kernel 1: block 0 = gated chain + middle chunk; 1..2048 = experts ----
// 64KB dynamic LDS (unused) -> 2 blocks/CU (R18/R21 A/B: best). Expert Wef
// reads NT (R19, -7.1us), part writes NT.
__global__ __launch_bounds__(256, 4) void k_mainc(
    const float* __restrict__ X,
    const float* __restrict__ bfv,
    const float* __restrict__ Wbf, const float* __restrict__ bbf,
    const float* __restrict__ Wbr, const float* __restrict__ bbr,
    const float* __restrict__ Wbo, const float* __restrict__ bbo,
    const float* __restrict__ Wm, const float* __restrict__ bm,
    const float* __restrict__ Wmo, const float* __restrict__ bmo,
    const float* __restrict__ Wa, const float* __restrict__ ba,
    const float* __restrict__ Wao, const float* __restrict__ bao,
    const float* __restrict__ Wef, const float* __restrict__ lw,
    float* __restrict__ out, float* __restrict__ ws)
{
    extern __shared__ float dynpad[];   // sized 64KB at launch; occupancy limiter
    __shared__ float sg[256];
    __shared__ float sacc[4][256];
    __shared__ float gl[288];
    __shared__ int   rlist[288];
    __shared__ int   swcnt[4];
    int b = blockIdx.x, t = threadIdx.x;
    int quad = t >> 6, lane = t & 63;
    float* part = ws + PART_OFF;

    if (b == 0) {
        // ---- base stack + middle, ReLU-gated gather matvecs (L3-warm) ----
        sg[t] = fmaxf(bfv[0] * Wbf[t] + bbf[t], 0.f);
        __syncthreads();
        head256(sg, sacc[0], sacc[1], Wbo, bbo, lw[0], out + 2, t);

        #define MV_GATED(W, B)                                                  \
        {                                                                       \
            int nr = compact_nz(sg[t], t, quad, lane, rlist, gl, swcnt);        \
            f4 a = gather8((const f4*)(W) + lane, rlist, gl, nr, quad);         \
            sacc[quad][lane*4+0] = a.x; sacc[quad][lane*4+1] = a.y;             \
            sacc[quad][lane*4+2] = a.z; sacc[quad][lane*4+3] = a.w;             \
            __syncthreads();                                                    \
            float v = fmaxf(sacc[0][t] + sacc[1][t] + sacc[2][t] + sacc[3][t]   \
                            + (B)[t], 0.f);                                     \
            __syncthreads();                                                    \
            sg[t] = v;                                                          \
            __syncthreads();                                                    \
        }

        for (int i = 0; i < 3; ++i) {
            MV_GATED(Wbr + i*65536, bbr + i*256);
            head256(sg, sacc[0], sacc[1], Wbo + (i+1)*512, bbo + (i+1)*2,
                    lw[i+1], out + 2 + (i+1)*2, t);
        }
        MV_GATED(Wm, bm);
        head256(sg, sacc[0], sacc[1], Wmo, bmo, lw[2056], out + 2 + 2056*2, t);

        // middle We_first chunk -> part row 0, gated by sg*lw[2056]
        {
            int nr = compact_nz(sg[t] * lw[2056], t, quad, lane, rlist, gl, swcnt);
            f4 a = gather8((const f4*)(Wef + (size_t)A_N * 65536) + lane,
                           rlist, gl, nr, quad);
            sacc[quad][lane*4+0] = a.x; sacc[quad][lane*4+1] = a.y;
            sacc[quad][lane*4+2] = a.z; sacc[quad][lane*4+3] = a.w;
            __syncthreads();
            part[t] = sacc[0][t] + sacc[1][t] + sacc[2][t] + sacc[3][t];
        }
        return;
    }

    // ---- expert path (compacted): idx = b-1 ----
    int idx = b - 1;
    int nact = ((const int*)ws)[NACTI_OFF];
    if (idx >= nact) return;            // instant exit (k_list zeroed out rows)
    int e = ((const int*)ws + LISTI_OFF)[idx];

    float xv = X[e];
    float w  = lw[4 + e];
    float h  = fmaxf(xv * Wa[e*256 + t] + ba[e*256 + t], 0.f);
    float2 wo = *(const float2*)&Wao[(size_t)e*512 + 2*t];
    sacc[0][t] = h * wo.x;
    sacc[1][t] = h * wo.y;
    __syncthreads();
    for (int s = 128; s > 0; s >>= 1) {
        if (t < s) { sacc[0][t] += sacc[0][t+s]; sacc[1][t] += sacc[1][t+s]; }
        __syncthreads();
    }
    if (t == 0) {
        float o0 = sacc[0][0] + bao[2*e], o1 = sacc[1][0] + bao[2*e+1];
        float m  = fmaxf(o0, o1);
        float e0 = expf(o0 - m), e1 = expf(o1 - m);
        float inv = w / (e0 + e1);      // * lw * mask; /wsum deferred
        out[2 + (4+e)*2]     = e0 * inv;
        out[2 + (4+e)*2 + 1] = e1 * inv;
    }
    float val = h * w;
    __syncthreads();

    int nr = compact_nz(val, t, quad, lane, rlist, gl, swcnt);
    f4 acc = gather8nt((const f4*)(Wef + (size_t)e * 65536) + lane, rlist, gl, nr, quad);
    sacc[quad][lane*4+0] = acc.x; sacc[quad][lane*4+1] = acc.y;
    sacc[quad][lane*4+2] = acc.z; sacc[quad][lane*4+3] = acc.w;
    __syncthreads();
    float pv = sacc[0][t] + sacc[1][t] + sacc[2][t] + sacc[3][t];
    __builtin_nontemporal_store(pv, &part[(size_t)(1+idx)*256 + t]);
}

// ---- kernel 2: pure reduce part rows 0..nact -> part2[64][256] ----
__global__ __launch_bounds__(256) void k_red(float* __restrict__ ws)
{
    int r = blockIdx.x, t = threadIdx.x;
    int nact = ((const int*)ws)[NACTI_OFF];
    float acc = 0.f;
    for (int j = r; j <= nact; j += 64) {
        acc += ws[PART_OFF + (size_t)j*256 + t];
    }
    ws[PART2_OFF + r*256 + t] = acc;
}

// ---- kernel 3: end stack + final combine (1 block x 1024, f4 matvecs) ----
__global__ __launch_bounds__(1024) void k_end(
    const float* __restrict__ bef, const float* __restrict__ Wer,
    const float* __restrict__ ber, const float* __restrict__ Weo,
    const float* __restrict__ beo, const float* __restrict__ lw,
    float* __restrict__ out, float* __restrict__ ws)
{
    __shared__ float sx[256];
    __shared__ float wacc[16][256];
    __shared__ float red0[1024], red1[1024];
    __shared__ float endraw[4][2];
    int tid = threadIdx.x;
    int w = tid >> 6, l = tid & 63;     // 16 waves x 64 lanes
    int q = tid >> 8, t = tid & 255;

    // ---- finish reduce: part2[64][256] -> sx, /gsum, bias, relu ----
    float acc = 0.f;
    #pragma unroll
    for (int j = 0; j < 16; ++j) acc += ws[PART2_OFF + (q*16 + j)*256 + t];
    wacc[q][t] = acc;
    __syncthreads();
    float gsum = ws[GSUM_OFF];
    if (tid < 256) {
        float v = wacc[0][t] + wacc[1][t] + wacc[2][t] + wacc[3][t];
        sx[t] = fmaxf(v / gsum + bef[t], 0.f);
    }
    __syncthreads();

    #define HEAD_G(W2, B2, SCALE, DEST)                                         \
    {                                                                           \
        if (tid < 256) { red0[tid] = sx[tid]*(W2)[2*tid]; red1[tid] = sx[tid]*(W2)[2*tid+1]; } \
        __syncthreads();                                                        \
        for (int s = 128; s > 0; s >>= 1) {                                     \
            if (tid < s) { red0[tid] += red0[tid+s]; red1[tid] += red1[tid+s]; }\
            __syncthreads();                                                    \
        }                                                                       \
        if (tid == 0) {                                                         \
            float o0 = red0[0] + (B2)[0], o1 = red1[0] + (B2)[1];               \
            float m  = fmaxf(o0, o1);                                           \
            float e0 = expf(o0 - m), e1 = expf(o1 - m);                         \
            float inv = (SCALE) / (e0 + e1);                                    \
            (DEST)[0] = e0 * inv; (DEST)[1] = e1 * inv;                         \
        }                                                                       \
        __syncthreads();                                                        \
    }

    // 16-way wave-K-split f4 matvec (fat registers OK in this standalone kernel)
    #define MV_E(W, B)                                                          \
    {                                                                           \
        const f4* Wv = (const f4*)(W);                                          \
        f4 a4 = {0.f, 0.f, 0.f, 0.f};                                           \
        _Pragma("unroll 16")                                                    \
        for (int kk = 0; kk < 16; ++kk) {                                       \
            int k = w*16 + kk;                                                  \
            float xv = sx[k];                                                   \
            f4 wv = Wv[k*64 + l];                                               \
            a4 += xv * wv;                                                      \
        }                                                                       \
        wacc[w][4*l+0] = a4.x; wacc[w][4*l+1] = a4.y;                           \
        wacc[w][4*l+2] = a4.z; wacc[w][4*l+3] = a4.w;                           \
        __syncthreads();                                                        \
        if (tid < 256) {                                                        \
            float v = 0.f;                                                      \
            _Pragma("unroll 16")                                                \
            for (int j = 0; j < 16; ++j) v += wacc[j][tid];                     \
            sx[tid] = fmaxf(v + (B)[tid], 0.f);                                 \
        }                                                                       \
        __syncthreads();                                                        \
    }

    HEAD_G(Weo, beo, lw[2052], &endraw[0][0]);
    for (int i = 0; i < 3; ++i) {
        MV_E(Wer + i*65536, ber + i*256);
        HEAD_G(Weo + (i+1)*512, beo + (i+1)*2, lw[2053 + i], &endraw[i+1][0]);
    }

    // ---- rescale all rows by 1/wsum, accumulate final logit ----
    float invw = 1.f / ws[WSUM_OFF];
    float s0 = 0.f, s1 = 0.f;
    for (int i = tid; i < NLAYERS; i += 1024) {
        float v0, v1;
        if (i >= 2052 && i < 2056) { v0 = endraw[i-2052][0]; v1 = endraw[i-2052][1]; }
        else                        { v0 = out[2 + 2*i];      v1 = out[2 + 2*i + 1]; }
        v0 *= invw; v1 *= invw;
        out[2 + 2*i]     = v0;
        out[2 + 2*i + 1] = v1;
        s0 += v0; s1 += v1;
    }
    red0[tid] = s0; red1[tid] = s1; __syncthreads();
    for (int s = 512; s > 0; s >>= 1) {
        if (tid < s) { red0[tid] += red0[tid+s]; red1[tid] += red1[tid+s]; }
        __syncthreads();
    }
    if (tid == 0) { out[0] = red0[0]; out[1] = red1[0]; }
}

extern "C" void kernel_launch(void* const* d_in, const int* in_sizes, int n_in,
                              void* d_out, int out_size, void* d_ws, size_t ws_size,
                              hipStream_t stream)
{
    const float* X    = (const float*)d_in[0];
    const int*   Xm   = (const int*)  d_in[1];
    const float* bfv  = (const float*)d_in[2];
    const float* Wbf  = (const float*)d_in[3];
    const float* bbf  = (const float*)d_in[4];
    const float* Wbr  = (const float*)d_in[5];
    const float* bbr  = (const float*)d_in[6];
    const float* Wbo  = (const float*)d_in[7];
    const float* bbo  = (const float*)d_in[8];
    const float* Wm   = (const float*)d_in[9];
    const float* bm   = (const float*)d_in[10];
    const float* Wmo  = (const float*)d_in[11];
    const float* bmo  = (const float*)d_in[12];
    const float* Wa   = (const float*)d_in[13];
    const float* ba   = (const float*)d_in[14];
    const float* Wao  = (const float*)d_in[15];
    const float* bao  = (const float*)d_in[16];
    const float* Wef  = (const float*)d_in[17];
    const float* bef  = (const float*)d_in[18];
    const float* Wer  = (const float*)d_in[19];
    const float* ber  = (const float*)d_in[20];
    const float* Weo  = (const float*)d_in[21];
    const float* beo  = (const float*)d_in[22];
    const float* lw   = (const float*)d_in[23];
    float* out = (float*)d_out;
    float* wsf = (float*)d_ws;

    k_list<<<36, 1024, 0, stream>>>(Xm, lw, Wbr, Wm, Wbo, Wmo, Wef,
                                    Wer, Weo, bef, ber, beo, out, wsf);
    k_mainc<<<A_N + 1, 256, 65536, stream>>>(X, bfv, Wbf, bbf, Wbr, bbr, Wbo, bbo,
                                             Wm, bm, Wmo, bmo, Wa, ba, Wao, bao,
                                             Wef, lw, out, wsf);
    k_red<<<64, 256, 0, stream>>>(wsf);
    k_end<<<1, 1024, 0, stream>>>(bef, Wer, ber, Weo, beo, lw, out, wsf);
}